// Round 20
// baseline (892.010 us; speedup 1.0000x reference)
//
#include <hip/hip_runtime.h>

typedef _Float16 f16;
typedef _Float16 f16x8 __attribute__((ext_vector_type(8)));
typedef _Float16 f16x4 __attribute__((ext_vector_type(4)));
typedef float    f32x4 __attribute__((ext_vector_type(4)));
typedef unsigned long long ull;

static constexpr int Bb  = 32;
static constexpr int Tt  = 128;
static constexpr int HID = 1024;
static constexpr int ZD  = 256;
static constexpr int DE  = 512;
static constexpr int VOC = 32000;
static constexpr int BT  = Bb * Tt;   // 4096
static constexpr int G4  = 4 * HID;   // 4096
static constexpr int NLSTM = 64;      // lstm-role blocks (16 hidden units each)
static constexpr int NCOL  = 125;     // worker columns (256-wide output panels)
static constexpr int NXGT  = 1024;    // xg 128x128 tiles (32 m x 32 n)
// HS layout is T-MAJOR: row m' = t*32 + b. Writes are agent-scope; all reads are
// flag-gated after the writes, so normal cached loads are coherent.
// XG GEMM is folded into the fused kernel's worker prologue (workers are idle
// until step 8 anyway); lstm blocks wait on xgdone + one-time acquire fence.

// ---- async global->LDS, 16B per lane; LDS dest = wave-uniform base + lane*16 ----
__device__ __forceinline__ void gld_lds16(const void* g, void* l) {
  __builtin_amdgcn_global_load_lds((const __attribute__((address_space(1))) unsigned int*)g,
                                   (__attribute__((address_space(3))) unsigned int*)l,
                                   16, 0, 0);
}

// ---------------- f32 -> f16 convert, 3 arrays in one launch ----------------
__global__ void cvt3_kernel(const float* __restrict__ a, f16* __restrict__ da, int na4,
                            const float* __restrict__ b, f16* __restrict__ db, int nb4,
                            const float* __restrict__ c, f16* __restrict__ dc, int nc4) {
  int i = blockIdx.x * blockDim.x + threadIdx.x;
  int st = gridDim.x * blockDim.x;
  int tot = na4 + nb4 + nc4;
  for (; i < tot; i += st) {
    const float* s; f16* d; int j = i;
    if (j < na4)              { s = a; d = da; }
    else if ((j -= na4) < nb4){ s = b; d = db; }
    else                      { j -= nb4; s = c; d = dc; }
    float4 v = ((const float4*)s)[j];
    f16x4 o = { (f16)v.x, (f16)v.y, (f16)v.z, (f16)v.w };
    ((f16x4*)d)[j] = o;
  }
}

// ---------------- embedding gather -> f16 ----------------
__global__ void gather_kernel(const float* __restrict__ emb, const int* __restrict__ x,
                              f16* __restrict__ E) {
  int g = blockIdx.x * 256 + threadIdx.x;   // BT*DE/8 threads
  int m = g >> 6, seg = (g & 63) * 8;
  int idx = x[m];
  const float* src = emb + (size_t)idx * DE + seg;
  float4 a = *(const float4*)src;
  float4 b = *(const float4*)(src + 4);
  f16x8 o = { (f16)a.x,(f16)a.y,(f16)a.z,(f16)a.w,(f16)b.x,(f16)b.y,(f16)b.z,(f16)b.w };
  *(f16x8*)(E + (size_t)m * DE + seg) = o;
}

// ---------------- bias sum ----------------
__global__ void bsum_kernel(const float* __restrict__ a, const float* __restrict__ b,
                            float* __restrict__ o, int n) {
  int i = blockIdx.x * blockDim.x + threadIdx.x;
  if (i < n) o[i] = a[i] + b[i];
}

// ---------------- h0 = tanh(z @ W_h^T + b_h), store f16 ----------------
__global__ __launch_bounds__(256) void h0_kernel(const float* __restrict__ z,
                                                 const float* __restrict__ W_h,
                                                 const float* __restrict__ b_h,
                                                 f16* __restrict__ h0f) {
  __shared__ float zs[32][260];
  __shared__ float wsl[8][260];
  const int jc = blockIdx.x, tid = threadIdx.x;
  #pragma unroll
  for (int it = 0; it < 8; ++it) {
    int idx = it * 256 + tid;
    float4 v = ((const float4*)z)[idx];
    int b = idx >> 6, k = (idx & 63) * 4;
    zs[b][k] = v.x; zs[b][k+1] = v.y; zs[b][k+2] = v.z; zs[b][k+3] = v.w;
  }
  #pragma unroll
  for (int it = 0; it < 2; ++it) {
    int idx = it * 256 + tid;
    float4 v = ((const float4*)(W_h + (size_t)jc * 8 * ZD))[idx];
    int r = idx >> 6, k = (idx & 63) * 4;
    wsl[r][k] = v.x; wsl[r][k+1] = v.y; wsl[r][k+2] = v.z; wsl[r][k+3] = v.w;
  }
  __syncthreads();
  const int b = tid >> 3, jj = tid & 7;
  const int j = jc * 8 + jj;
  float acc = b_h[j];
  for (int k = 0; k < ZD; ++k) acc += zs[b][k] * wsl[jj][k];
  h0f[(size_t)b * HID + j] = (f16)tanhf(acc);
}

// =================================================================================
// FUSED persistent kernel: 256 blocks x 512 threads, 1 block/CU (capacity-resident).
//   blocks 0..63   : LSTM recurrence (t-major HS); waits for xgdone first.
//   blocks 64..188 : phase 0 = xg 128x128 tiles (threads 0..255), publish xgdone;
//                    phase 1 = static ng-owned output-GEMM panels, mg 0..15.
//   blocks 189..255: exit immediately.
// =================================================================================
static constexpr int SM_HL   = 0;                       // f16 hl[32][1032] = 66048 B
static constexpr int SM_PART = 66048;                   // float part[8][64][33] = 67584 B
static constexpr int SM_FL   = 133632;                  // unsigned fl[64] mirror = 256 B
static constexpr int SM_SIZE = 133904;

__device__ void lstm_role(const f16* __restrict__ Whh16, const float* __restrict__ XG2,
                          const f16* __restrict__ h0f, f16* __restrict__ HS,
                          unsigned* __restrict__ bar, unsigned* __restrict__ gready,
                          unsigned* __restrict__ xgdone, char* smem) {
  const int bid = blockIdx.x, tid = threadIdx.x;
  const int lane = tid & 63, wid = tid >> 6;
  const int lr = lane & 15, hi = lane >> 4;
  const int j0 = bid * 16;
  f16 (*hl)[1032] = (f16 (*)[1032])(smem + SM_HL);
  float (*part)[64][33] = (float (*)[64][33])(smem + SM_PART);
  unsigned* fl = (unsigned*)(smem + SM_FL);

  if (tid < 64) fl[tid] = 0;

  f16x8 wfrag[4][4];
  #pragma unroll
  for (int rt = 0; rt < 4; ++rt) {
    int g = rt * HID + j0 + lr;
    #pragma unroll
    for (int kk = 0; kk < 4; ++kk)
      wfrag[rt][kk] = *(const f16x8*)(Whh16 + (size_t)g * HID + wid * 128 + kk * 32 + hi * 8);
  }

  // wait for workers to finish the in-fused XG GEMM, then one-time acquire
  if (tid == 0) {
    while (__hip_atomic_load(xgdone, __ATOMIC_RELAXED, __HIP_MEMORY_SCOPE_AGENT) < (unsigned)NCOL)
      __builtin_amdgcn_s_sleep(16);
  }
  __syncthreads();
  __builtin_amdgcn_fence(__ATOMIC_ACQUIRE, "agent");

  const int ub = tid & 15, bb = tid >> 4;
  float creg = 0.f;
  __syncthreads();   // fl init + fence done

  for (int t = 0; t < Tt; ++t) {
    float xg[4];
    #pragma unroll
    for (int q = 0; q < 4; ++q)
      xg[q] = XG2[((size_t)(q * HID + j0 + ub) * 32 + bb) * 128 + t];

    // ---- per-wave readiness: wave 0 polls bar + mirrors to LDS; waves 1..7
    //      spin on the LDS mirror for THEIR 8 producers only ----
    if (t > 0) {
      if (wid == 0) {
        for (;;) {
          unsigned f = __hip_atomic_load(&bar[lane], __ATOMIC_RELAXED, __HIP_MEMORY_SCOPE_AGENT);
          __hip_atomic_store(&fl[lane], f, __ATOMIC_RELAXED, __HIP_MEMORY_SCOPE_WORKGROUP);
          if (__all(f >= (unsigned)t)) break;
        }
        if (bid == 0 && lane == 0)
          __hip_atomic_store(gready, (unsigned)t, __ATOMIC_RELAXED, __HIP_MEMORY_SCOPE_AGENT);
      } else {
        const int p = wid * 8 + (lane & 7);
        for (;;) {
          unsigned f = __hip_atomic_load(&fl[p], __ATOMIC_RELAXED, __HIP_MEMORY_SCOPE_WORKGROUP);
          if (__all(f >= (unsigned)t)) break;
        }
      }
    }

    // ---- stage own k-slice: wave wid loads ALL 32 batch rows x units
    //      [wid*128, wid*128+128) -- wave-private, no barrier needed ----
    {
      const int uo = wid * 128 + (lane & 31) * 4;   // ull = 4 units
      #pragma unroll
      for (int ps = 0; ps < 16; ++ps) {
        int row = ps * 2 + (lane >> 5);
        const f16* hb = (t == 0) ? (h0f + (size_t)row * HID)
                                 : (HS + (size_t)((t - 1) * 32 + row) * HID);
        ull v = *(const ull*)(hb + uo);
        *(ull*)&hl[row][uo] = v;
      }
    }

    // ---- gate MFMA: C[64 gate rows][32 batches], this wave's k-eighth ----
    {
      f32x4 acc[4][2] = {};
      #pragma unroll
      for (int kk = 0; kk < 4; ++kk) {
        int ko = wid * 128 + kk * 32 + hi * 8;
        f16x8 bf0 = *(const f16x8*)&hl[lr][ko];
        f16x8 bf1 = *(const f16x8*)&hl[16 + lr][ko];
        #pragma unroll
        for (int rt = 0; rt < 4; ++rt) {
          acc[rt][0] = __builtin_amdgcn_mfma_f32_16x16x32_f16(wfrag[rt][kk], bf0, acc[rt][0], 0, 0, 0);
          acc[rt][1] = __builtin_amdgcn_mfma_f32_16x16x32_f16(wfrag[rt][kk], bf1, acc[rt][1], 0, 0, 0);
        }
      }
      #pragma unroll
      for (int rt = 0; rt < 4; ++rt)
        #pragma unroll
        for (int bt = 0; bt < 2; ++bt)
          #pragma unroll
          for (int p = 0; p < 4; ++p)
            part[wid][rt * 16 + hi * 4 + p][bt * 16 + lr] = acc[rt][bt][p];
    }
    __syncthreads();   // S1: part complete (and all waves past their hl reads)

    // ---- LSTM update: thread (ub, bb); h store agent-coherent 2B, t-major ----
    {
      float g4[4];
      #pragma unroll
      for (int q = 0; q < 4; ++q) {
        int i = q * 16 + ub;
        float s = xg[q];
        #pragma unroll
        for (int w = 0; w < 8; ++w) s += part[w][i][bb];
        g4[q] = s;
      }
      float ig = 1.f / (1.f + __expf(-g4[0]));
      float fg = 1.f / (1.f + __expf(-g4[1]));
      float gg = tanhf(g4[2]);
      float og = 1.f / (1.f + __expf(-g4[3]));
      creg = fg * creg + ig * gg;
      float h = og * tanhf(creg);
      union { f16 h; unsigned short u; } cv;
      cv.h = (f16)h;
      __hip_atomic_store((unsigned short*)&HS[(size_t)(t * 32 + bb) * HID + j0 + ub],
                         cv.u, __ATOMIC_RELAXED, __HIP_MEMORY_SCOPE_AGENT);
    }

    // ---- drain + flag (every t; workers need t=127 too) ----
    asm volatile("s_waitcnt vmcnt(0)" ::: "memory");
    __syncthreads();   // S2: all h stores at IF
    if (tid == 0)
      __hip_atomic_store(&bar[bid], (unsigned)(t + 1),
                         __ATOMIC_RELAXED, __HIP_MEMORY_SCOPE_AGENT);
  }

  // block 0: final aggregation (flags reach 128 only after all finish t=127)
  if (bid == 0) {
    if (wid == 0) {
      for (;;) {
        unsigned f = __hip_atomic_load(&bar[lane], __ATOMIC_RELAXED, __HIP_MEMORY_SCOPE_AGENT);
        if (__all(f >= (unsigned)Tt)) break;
      }
      if (lane == 0)
        __hip_atomic_store(gready, (unsigned)Tt, __ATOMIC_RELAXED, __HIP_MEMORY_SCOPE_AGENT);
    }
    __syncthreads();
  }
}

__device__ void worker_role(const f16* __restrict__ HS, const f16* __restrict__ Wout16,
                            const float* __restrict__ b_out, float* __restrict__ out,
                            unsigned* __restrict__ gready, unsigned* __restrict__ xgdone,
                            const f16* __restrict__ E16, const f16* __restrict__ Wih16,
                            const float* __restrict__ bs, float* __restrict__ XG2,
                            char* smem) {
  const int ng = blockIdx.x - NLSTM;           // static column ownership
  const int tid = threadIdx.x, wid = tid >> 6, lane = tid & 63;
  const int wm = wid >> 2, wn = wid & 3;
  const int lr = lane & 15, hi = lane >> 4;
  const int srow = lane >> 2;
  const int scol = ((lane & 3) ^ ((lane >> 3) & 3)) * 8;   // pre-swizzled source col
  const int sx   = (hi ^ ((lr >> 1) & 3)) * 8;             // swizzled read slot
  f16* As = (f16*)(smem);            // [4][8192] halves = 65536 B
  f16* Bs = (f16*)(smem + 65536);    // [4][8192]
  const int cb0 = wid * 2, cb1 = wid * 2 + 1;
  const int n0 = ng * 256;

  // ---- Phase 0: XG GEMM tiles (128x128, threads 0..255 active) ----
  {
    f16* As2 = (f16*)(smem);
    f16* Bs2 = (f16*)(smem + 16384);
    const bool act = tid < 256;
    const int w4 = tid >> 6;                    // 0..3 when act
    const int wmx = (w4 >> 1) & 1, wnx = w4 & 1;
    const int sr = lane >> 3, sk = (lane & 7) * 8;
    for (int xt = ng; xt < NXGT; xt += NCOL) {
      const int xn = xt & 31, xm = xt >> 5;
      const int n0x = xn * 128, m0x = xm * 128;
      f32x4 xacc[4][4] = {};
      for (int k0 = 0; k0 < DE; k0 += 64) {
        __syncthreads();
        if (act) {
          #pragma unroll
          for (int i = 0; i < 4; ++i) {
            int rr = (w4 * 4 + i) * 8;
            gld_lds16(E16   + (size_t)(m0x + rr + sr) * DE + k0 + sk, As2 + rr * 64);
            gld_lds16(Wih16 + (size_t)(n0x + rr + sr) * DE + k0 + sk, Bs2 + rr * 64);
          }
        }
        __syncthreads();
        if (act) {
          #pragma unroll
          for (int ks = 0; ks < 2; ++ks) {
            f16x8 af[4], bf[4];
            #pragma unroll
            for (int mt = 0; mt < 4; ++mt)
              af[mt] = *(const f16x8*)&As2[(wmx * 64 + mt * 16 + lr) * 64 + ks * 32 + hi * 8];
            #pragma unroll
            for (int nt = 0; nt < 4; ++nt)
              bf[nt] = *(const f16x8*)&Bs2[(wnx * 64 + nt * 16 + lr) * 64 + ks * 32 + hi * 8];
            #pragma unroll
            for (int mt = 0; mt < 4; ++mt)
              #pragma unroll
              for (int nt = 0; nt < 4; ++nt)
                xacc[mt][nt] = __builtin_amdgcn_mfma_f32_16x16x32_f16(af[mt], bf[nt], xacc[mt][nt], 0, 0, 0);
          }
        }
      }
      if (act) {
        #pragma unroll
        for (int nt = 0; nt < 4; ++nt) {
          int col = n0x + wnx * 64 + nt * 16 + lr;
          float bv = bs[col];
          #pragma unroll
          for (int mt = 0; mt < 4; ++mt) {
            int row = m0x + wmx * 64 + mt * 16 + hi * 4;
            int b = row >> 7, t0 = row & 127;
            float4 v = { xacc[mt][nt][0] + bv, xacc[mt][nt][1] + bv,
                         xacc[mt][nt][2] + bv, xacc[mt][nt][3] + bv };
            *(float4*)&XG2[((size_t)col * 32 + b) * 128 + t0] = v;
          }
        }
      }
      __syncthreads();
    }
    __threadfence();   // release: XG2 stores -> coherence point (wbl2)
    __syncthreads();
    if (tid == 0)
      __hip_atomic_fetch_add(xgdone, 1u, __ATOMIC_RELEASE, __HIP_MEMORY_SCOPE_AGENT);
  }

  // ---- Phase 1: output GEMM panels, mg 0..15 ----
  for (int mg = 0; mg < 16; ++mg) {
    // readiness: all lstm blocks completed step 8*mg+7 (gready >= 8mg+8)
    if (wid == 0) {
      const unsigned tgt = (unsigned)(8 * mg + 8);
      for (;;) {
        unsigned g = __hip_atomic_load(gready, __ATOMIC_RELAXED, __HIP_MEMORY_SCOPE_AGENT);
        if (g >= tgt) break;
        __builtin_amdgcn_s_sleep(64);
      }
    }
    __syncthreads();
    // stagger the 125-block fetch burst: ~(ng&31) x 70ns busy-wait (no imm needed)
    {
      ull t0 = __builtin_amdgcn_s_memtime();
      ull dl = (ull)((ng & 31) * 100);
      while (__builtin_amdgcn_s_memtime() - t0 < dl) { }
    }

    const int m0 = mg * 256;
    f32x4 acc[8][4] = {};

    auto STAGE = [&](int kt) {
      const int k0 = kt << 5, buf = kt & 3;
      gld_lds16(HS     + (size_t)(m0 + cb0 * 16 + srow) * HID + k0 + scol, As + buf * 8192 + cb0 * 512);
      gld_lds16(Wout16 + (size_t)(n0 + cb0 * 16 + srow) * HID + k0 + scol, Bs + buf * 8192 + cb0 * 512);
      gld_lds16(HS     + (size_t)(m0 + cb1 * 16 + srow) * HID + k0 + scol, As + buf * 8192 + cb1 * 512);
      gld_lds16(Wout16 + (size_t)(n0 + cb1 * 16 + srow) * HID + k0 + scol, Bs + buf * 8192 + cb1 * 512);
    };

    STAGE(0); STAGE(1); STAGE(2);
    for (int kt = 0; kt < 32; ++kt) {
      if (kt < 30)       asm volatile("s_waitcnt vmcnt(8)" ::: "memory");
      else if (kt == 30) asm volatile("s_waitcnt vmcnt(4)" ::: "memory");
      else               asm volatile("s_waitcnt vmcnt(0)" ::: "memory");
      __builtin_amdgcn_s_barrier();
      if (kt + 3 < 32) STAGE(kt + 3);
      const f16* as = As + (kt & 3) * 8192;
      const f16* bs2 = Bs + (kt & 3) * 8192;
      f16x8 af[8], bf[4];
      #pragma unroll
      for (int mt = 0; mt < 8; ++mt)
        af[mt] = *(const f16x8*)&as[(wm * 128 + mt * 16 + lr) * 32 + sx];
      #pragma unroll
      for (int nt = 0; nt < 4; ++nt)
        bf[nt] = *(const f16x8*)&bs2[(wn * 64 + nt * 16 + lr) * 32 + sx];
      __builtin_amdgcn_s_setprio(1);
      #pragma unroll
      for (int mt = 0; mt < 8; ++mt)
        #pragma unroll
        for (int nt = 0; nt < 4; ++nt)
          acc[mt][nt] = __builtin_amdgcn_mfma_f32_16x16x32_f16(af[mt], bf[nt], acc[mt][nt], 0, 0, 0);
      __builtin_amdgcn_s_setprio(0);
    }

    // epilogue: un-permute rows (m' = t*32+b -> out row b*128+t), add bias,
    // NON-TEMPORAL stores (out is write-once; keep it out of the caches)
    #pragma unroll
    for (int nt = 0; nt < 4; ++nt) {
      int col = n0 + wn * 64 + nt * 16 + lr;
      float bv = b_out[col];
      #pragma unroll
      for (int mt = 0; mt < 8; ++mt) {
        int mbase = m0 + wm * 128 + mt * 16 + hi * 4;
        #pragma unroll
        for (int p = 0; p < 4; ++p) {
          int mp = mbase + p;
          int orow = (mp & 31) * 128 + (mp >> 5);
          __builtin_nontemporal_store(acc[mt][nt][p] + bv,
                                      &out[(size_t)orow * VOC + col]);
        }
      }
    }
    __syncthreads();   // all frag reads done before next tile's STAGE overwrites LDS
  }
}

__global__ __launch_bounds__(512, 1) void fused_kernel(
    const f16* __restrict__ Whh16, const float* __restrict__ XG2c,
    const f16* __restrict__ h0f, f16* __restrict__ HS,
    const f16* __restrict__ Wout16, const float* __restrict__ b_out,
    float* __restrict__ out, unsigned* __restrict__ bar,
    unsigned* __restrict__ gready, unsigned* __restrict__ xgdone,
    const f16* __restrict__ E16, const f16* __restrict__ Wih16,
    const float* __restrict__ bs, float* __restrict__ XG2) {
  __shared__ __align__(16) char smem[SM_SIZE];
  if (blockIdx.x < NLSTM) {
    lstm_role(Whh16, XG2c, h0f, HS, bar, gready, xgdone, smem);
  } else if (blockIdx.x < NLSTM + NCOL) {
    worker_role(HS, Wout16, b_out, out, gready, xgdone, E16, Wih16, bs, XG2, smem);
  }
}

extern "C" void kernel_launch(void* const* d_in, const int* in_sizes, int n_in,
                              void* d_out, int out_size, void* d_ws, size_t ws_size,
                              hipStream_t stream) {
  const float* z     = (const float*)d_in[0];
  const int*   x     = (const int*)d_in[1];
  const float* W_h   = (const float*)d_in[2];
  const float* b_h   = (const float*)d_in[3];
  const float* emb   = (const float*)d_in[4];
  const float* W_ih  = (const float*)d_in[5];
  const float* W_hh  = (const float*)d_in[6];
  const float* b_ih  = (const float*)d_in[7];
  const float* b_hh  = (const float*)d_in[8];
  const float* W_out = (const float*)d_in[9];
  const float* b_out = (const float*)d_in[10];
  float* out = (float*)d_out;

  char* ws = (char*)d_ws;
  size_t off = 0;
  auto carve = [&](size_t n) { char* p = ws + off; off += (n + 255) & ~(size_t)255; return p; };
  f16*   E16    = (f16*)carve((size_t)BT * DE * 2);     // 4 MB
  f16*   Wih16  = (f16*)carve((size_t)G4 * DE * 2);     // 4 MB
  f16*   Whh16  = (f16*)carve((size_t)G4 * HID * 2);    // 8 MB
  f16*   Wout16 = (f16*)carve((size_t)VOC * HID * 2);   // 64 MB
  float* XG2    = (float*)carve((size_t)BT * G4 * 4);   // 64 MB, [g][b][t]
  f16*   HS     = (f16*)carve((size_t)BT * HID * 2);    // 8 MB, t-major rows
  f16*   h0f    = (f16*)carve((size_t)Bb * HID * 2);
  float* bs     = (float*)carve((size_t)G4 * 4);
  unsigned* bar    = (unsigned*)carve(256);
  unsigned* gready = (unsigned*)carve(256);
  unsigned* xgdone = (unsigned*)carve(256);

  (void)hipMemsetAsync(bar, 0, 768, stream);   // bar + gready + xgdone (contiguous)

  cvt3_kernel<<<2048, 256, 0, stream>>>(W_ih,  Wih16,  G4 * DE / 4,
                                        W_hh,  Whh16,  G4 * HID / 4,
                                        W_out, Wout16, VOC * HID / 4);
  gather_kernel<<<BT * DE / 8 / 256, 256, 0, stream>>>(emb, x, E16);
  bsum_kernel<<<16, 256, 0, stream>>>(b_ih, b_hh, bs, G4);
  h0_kernel<<<128, 256, 0, stream>>>(z, W_h, b_h, h0f);

  fused_kernel<<<256, 512, 0, stream>>>(Whh16, XG2, h0f, HS, Wout16, b_out, out,
                                        bar, gready, xgdone, E16, Wih16, bs, XG2);
}

// Round 21
// 798.632 us; speedup vs baseline: 1.1169x; 1.1169x over previous
//
#include <hip/hip_runtime.h>

typedef _Float16 f16;
typedef _Float16 f16x8 __attribute__((ext_vector_type(8)));
typedef _Float16 f16x4 __attribute__((ext_vector_type(4)));
typedef float    f32x4 __attribute__((ext_vector_type(4)));
typedef unsigned long long ull;

static constexpr int Bb  = 32;
static constexpr int Tt  = 128;
static constexpr int HID = 1024;
static constexpr int ZD  = 256;
static constexpr int DE  = 512;
static constexpr int VOC = 32000;
static constexpr int BT  = Bb * Tt;   // 4096
static constexpr int G4  = 4 * HID;   // 4096
static constexpr int NLSTM = 64;      // lstm-role blocks (16 hidden units each)
static constexpr int NCOL  = 125;     // worker columns (256-wide output panels)
// HS layout is T-MAJOR: row m' = t*32 + b. Writes are agent-scope; all reads are
// flag-gated after the writes, so normal cached loads are coherent.
// Workers: STATIC ng-ownership (block 64+ng owns column panel ng, iterates mg
// 0..15 in order); NON-TEMPORAL out stores keep the caches for Wout/XG.

// ---- async global->LDS, 16B per lane; LDS dest = wave-uniform base + lane*16 ----
__device__ __forceinline__ void gld_lds16(const void* g, void* l) {
  __builtin_amdgcn_global_load_lds((const __attribute__((address_space(1))) unsigned int*)g,
                                   (__attribute__((address_space(3))) unsigned int*)l,
                                   16, 0, 0);
}

// ---------------- f32 -> f16 convert, 3 arrays in one launch ----------------
__global__ void cvt3_kernel(const float* __restrict__ a, f16* __restrict__ da, int na4,
                            const float* __restrict__ b, f16* __restrict__ db, int nb4,
                            const float* __restrict__ c, f16* __restrict__ dc, int nc4) {
  int i = blockIdx.x * blockDim.x + threadIdx.x;
  int st = gridDim.x * blockDim.x;
  int tot = na4 + nb4 + nc4;
  for (; i < tot; i += st) {
    const float* s; f16* d; int j = i;
    if (j < na4)              { s = a; d = da; }
    else if ((j -= na4) < nb4){ s = b; d = db; }
    else                      { j -= nb4; s = c; d = dc; }
    float4 v = ((const float4*)s)[j];
    f16x4 o = { (f16)v.x, (f16)v.y, (f16)v.z, (f16)v.w };
    ((f16x4*)d)[j] = o;
  }
}

// ---------------- embedding gather -> f16 ----------------
__global__ void gather_kernel(const float* __restrict__ emb, const int* __restrict__ x,
                              f16* __restrict__ E) {
  int g = blockIdx.x * 256 + threadIdx.x;   // BT*DE/8 threads
  int m = g >> 6, seg = (g & 63) * 8;
  int idx = x[m];
  const float* src = emb + (size_t)idx * DE + seg;
  float4 a = *(const float4*)src;
  float4 b = *(const float4*)(src + 4);
  f16x8 o = { (f16)a.x,(f16)a.y,(f16)a.z,(f16)a.w,(f16)b.x,(f16)b.y,(f16)b.z,(f16)b.w };
  *(f16x8*)(E + (size_t)m * DE + seg) = o;
}

// ---------------- bias sum ----------------
__global__ void bsum_kernel(const float* __restrict__ a, const float* __restrict__ b,
                            float* __restrict__ o, int n) {
  int i = blockIdx.x * blockDim.x + threadIdx.x;
  if (i < n) o[i] = a[i] + b[i];
}

// ---------------- h0 = tanh(z @ W_h^T + b_h), store f16 ----------------
__global__ __launch_bounds__(256) void h0_kernel(const float* __restrict__ z,
                                                 const float* __restrict__ W_h,
                                                 const float* __restrict__ b_h,
                                                 f16* __restrict__ h0f) {
  __shared__ float zs[32][260];
  __shared__ float wsl[8][260];
  const int jc = blockIdx.x, tid = threadIdx.x;
  #pragma unroll
  for (int it = 0; it < 8; ++it) {
    int idx = it * 256 + tid;
    float4 v = ((const float4*)z)[idx];
    int b = idx >> 6, k = (idx & 63) * 4;
    zs[b][k] = v.x; zs[b][k+1] = v.y; zs[b][k+2] = v.z; zs[b][k+3] = v.w;
  }
  #pragma unroll
  for (int it = 0; it < 2; ++it) {
    int idx = it * 256 + tid;
    float4 v = ((const float4*)(W_h + (size_t)jc * 8 * ZD))[idx];
    int r = idx >> 6, k = (idx & 63) * 4;
    wsl[r][k] = v.x; wsl[r][k+1] = v.y; wsl[r][k+2] = v.z; wsl[r][k+3] = v.w;
  }
  __syncthreads();
  const int b = tid >> 3, jj = tid & 7;
  const int j = jc * 8 + jj;
  float acc = b_h[j];
  for (int k = 0; k < ZD; ++k) acc += zs[b][k] * wsl[jj][k];
  h0f[(size_t)b * HID + j] = (f16)tanhf(acc);
}

// ---------------- GEMM 128x128 (proven): C = A @ B^T + bias, XG output layout ---
__global__ __launch_bounds__(256, 2) void gemmxg_kernel(
    const f16* __restrict__ A, const f16* __restrict__ B,
    const float* __restrict__ bias, float* __restrict__ C,
    int M, int N, int K) {
  __shared__ f16 As[128 * 64];
  __shared__ f16 Bs[128 * 64];
  const int n0 = blockIdx.x * 128, m0 = blockIdx.y * 128;
  const int tid = threadIdx.x, wid = tid >> 6, lane = tid & 63;
  const int wm = wid >> 1, wn = wid & 1;
  const int sr = lane >> 3, sk = (lane & 7) * 8;
  f32x4 acc[4][4] = {};
  for (int k0 = 0; k0 < K; k0 += 64) {
    __syncthreads();
    #pragma unroll
    for (int i = 0; i < 4; ++i) {
      int rr = (wid * 4 + i) * 8;
      gld_lds16(A + (size_t)(m0 + rr + sr) * K + k0 + sk, &As[rr * 64]);
      gld_lds16(B + (size_t)(n0 + rr + sr) * K + k0 + sk, &Bs[rr * 64]);
    }
    __syncthreads();
    #pragma unroll
    for (int ks = 0; ks < 2; ++ks) {
      f16x8 af[4], bf[4];
      #pragma unroll
      for (int mt = 0; mt < 4; ++mt)
        af[mt] = *(const f16x8*)&As[(wm * 64 + mt * 16 + (lane & 15)) * 64 + ks * 32 + (lane >> 4) * 8];
      #pragma unroll
      for (int nt = 0; nt < 4; ++nt)
        bf[nt] = *(const f16x8*)&Bs[(wn * 64 + nt * 16 + (lane & 15)) * 64 + ks * 32 + (lane >> 4) * 8];
      #pragma unroll
      for (int mt = 0; mt < 4; ++mt)
        #pragma unroll
        for (int nt = 0; nt < 4; ++nt)
          acc[mt][nt] = __builtin_amdgcn_mfma_f32_16x16x32_f16(af[mt], bf[nt], acc[mt][nt], 0, 0, 0);
    }
  }
  #pragma unroll
  for (int nt = 0; nt < 4; ++nt) {
    int col = n0 + wn * 64 + nt * 16 + (lane & 15);
    float bv = bias[col];
    #pragma unroll
    for (int mt = 0; mt < 4; ++mt) {
      int row = m0 + wm * 64 + mt * 16 + (lane >> 4) * 4;
      int b = row >> 7, t0 = row & 127;
      float4 v = { acc[mt][nt][0] + bv, acc[mt][nt][1] + bv,
                   acc[mt][nt][2] + bv, acc[mt][nt][3] + bv };
      *(float4*)&C[((size_t)col * 32 + b) * 128 + t0] = v;
    }
  }
}

// =================================================================================
// FUSED persistent kernel: 256 blocks x 512 threads, 1 block/CU (capacity-resident).
//   blocks 0..63   : LSTM recurrence role (t-major HS), then exit.
//   blocks 64..188 : GEMM workers, STATIC ng-ownership (ng = bid-64), mg 0..15.
//   blocks 189..255: exit immediately.
// =================================================================================
static constexpr int SM_HL   = 0;                       // f16 hl[32][1032] = 66048 B
static constexpr int SM_PART = 66048;                   // float part[8][64][33] = 67584 B
static constexpr int SM_FL   = 133632;                  // unsigned fl[64] mirror = 256 B
static constexpr int SM_SIZE = 133904;

__device__ void lstm_role(const f16* __restrict__ Whh16, const float* __restrict__ XG2,
                          const f16* __restrict__ h0f, f16* __restrict__ HS,
                          unsigned* __restrict__ bar, unsigned* __restrict__ gready,
                          char* smem) {
  const int bid = blockIdx.x, tid = threadIdx.x;
  const int lane = tid & 63, wid = tid >> 6;
  const int lr = lane & 15, hi = lane >> 4;
  const int j0 = bid * 16;
  f16 (*hl)[1032] = (f16 (*)[1032])(smem + SM_HL);
  float (*part)[64][33] = (float (*)[64][33])(smem + SM_PART);
  unsigned* fl = (unsigned*)(smem + SM_FL);

  if (tid < 64) fl[tid] = 0;

  f16x8 wfrag[4][4];
  #pragma unroll
  for (int rt = 0; rt < 4; ++rt) {
    int g = rt * HID + j0 + lr;
    #pragma unroll
    for (int kk = 0; kk < 4; ++kk)
      wfrag[rt][kk] = *(const f16x8*)(Whh16 + (size_t)g * HID + wid * 128 + kk * 32 + hi * 8);
  }

  const int ub = tid & 15, bb = tid >> 4;
  float creg = 0.f;
  __syncthreads();   // fl init visible

  for (int t = 0; t < Tt; ++t) {
    float xg[4];
    #pragma unroll
    for (int q = 0; q < 4; ++q)
      xg[q] = XG2[((size_t)(q * HID + j0 + ub) * 32 + bb) * 128 + t];

    // ---- per-wave readiness: wave 0 polls bar + mirrors to LDS; waves 1..7
    //      spin on the LDS mirror for THEIR 8 producers only ----
    if (t > 0) {
      if (wid == 0) {
        for (;;) {
          unsigned f = __hip_atomic_load(&bar[lane], __ATOMIC_RELAXED, __HIP_MEMORY_SCOPE_AGENT);
          __hip_atomic_store(&fl[lane], f, __ATOMIC_RELAXED, __HIP_MEMORY_SCOPE_WORKGROUP);
          if (__all(f >= (unsigned)t)) break;
        }
        if (bid == 0 && lane == 0)
          __hip_atomic_store(gready, (unsigned)t, __ATOMIC_RELAXED, __HIP_MEMORY_SCOPE_AGENT);
      } else {
        const int p = wid * 8 + (lane & 7);
        for (;;) {
          unsigned f = __hip_atomic_load(&fl[p], __ATOMIC_RELAXED, __HIP_MEMORY_SCOPE_WORKGROUP);
          if (__all(f >= (unsigned)t)) break;
        }
      }
    }

    // ---- stage own k-slice: wave wid loads ALL 32 batch rows x units
    //      [wid*128, wid*128+128) -- wave-private, no barrier needed ----
    {
      const int uo = wid * 128 + (lane & 31) * 4;   // ull = 4 units
      #pragma unroll
      for (int ps = 0; ps < 16; ++ps) {
        int row = ps * 2 + (lane >> 5);
        const f16* hb = (t == 0) ? (h0f + (size_t)row * HID)
                                 : (HS + (size_t)((t - 1) * 32 + row) * HID);
        ull v = *(const ull*)(hb + uo);
        *(ull*)&hl[row][uo] = v;
      }
    }

    // ---- gate MFMA: C[64 gate rows][32 batches], this wave's k-eighth ----
    {
      f32x4 acc[4][2] = {};
      #pragma unroll
      for (int kk = 0; kk < 4; ++kk) {
        int ko = wid * 128 + kk * 32 + hi * 8;
        f16x8 bf0 = *(const f16x8*)&hl[lr][ko];
        f16x8 bf1 = *(const f16x8*)&hl[16 + lr][ko];
        #pragma unroll
        for (int rt = 0; rt < 4; ++rt) {
          acc[rt][0] = __builtin_amdgcn_mfma_f32_16x16x32_f16(wfrag[rt][kk], bf0, acc[rt][0], 0, 0, 0);
          acc[rt][1] = __builtin_amdgcn_mfma_f32_16x16x32_f16(wfrag[rt][kk], bf1, acc[rt][1], 0, 0, 0);
        }
      }
      #pragma unroll
      for (int rt = 0; rt < 4; ++rt)
        #pragma unroll
        for (int bt = 0; bt < 2; ++bt)
          #pragma unroll
          for (int p = 0; p < 4; ++p)
            part[wid][rt * 16 + hi * 4 + p][bt * 16 + lr] = acc[rt][bt][p];
    }
    __syncthreads();   // S1: part complete (and all waves past their hl reads)

    // ---- LSTM update: thread (ub, bb); h store agent-coherent 2B, t-major ----
    {
      float g4[4];
      #pragma unroll
      for (int q = 0; q < 4; ++q) {
        int i = q * 16 + ub;
        float s = xg[q];
        #pragma unroll
        for (int w = 0; w < 8; ++w) s += part[w][i][bb];
        g4[q] = s;
      }
      float ig = 1.f / (1.f + __expf(-g4[0]));
      float fg = 1.f / (1.f + __expf(-g4[1]));
      float gg = tanhf(g4[2]);
      float og = 1.f / (1.f + __expf(-g4[3]));
      creg = fg * creg + ig * gg;
      float h = og * tanhf(creg);
      union { f16 h; unsigned short u; } cv;
      cv.h = (f16)h;
      __hip_atomic_store((unsigned short*)&HS[(size_t)(t * 32 + bb) * HID + j0 + ub],
                         cv.u, __ATOMIC_RELAXED, __HIP_MEMORY_SCOPE_AGENT);
    }

    // ---- drain + flag (every t; workers need t=127 too) ----
    asm volatile("s_waitcnt vmcnt(0)" ::: "memory");
    __syncthreads();   // S2: all h stores at IF
    if (tid == 0)
      __hip_atomic_store(&bar[bid], (unsigned)(t + 1),
                         __ATOMIC_RELAXED, __HIP_MEMORY_SCOPE_AGENT);
  }

  // block 0: final aggregation (flags reach 128 only after all finish t=127)
  if (bid == 0) {
    if (wid == 0) {
      for (;;) {
        unsigned f = __hip_atomic_load(&bar[lane], __ATOMIC_RELAXED, __HIP_MEMORY_SCOPE_AGENT);
        if (__all(f >= (unsigned)Tt)) break;
      }
      if (lane == 0)
        __hip_atomic_store(gready, (unsigned)Tt, __ATOMIC_RELAXED, __HIP_MEMORY_SCOPE_AGENT);
    }
    __syncthreads();
  }
}

__device__ void worker_role(const f16* __restrict__ HS, const f16* __restrict__ Wout16,
                            const float* __restrict__ b_out, float* __restrict__ out,
                            unsigned* __restrict__ gready, char* smem) {
  const int ng = blockIdx.x - NLSTM;           // static column ownership
  const int tid = threadIdx.x, wid = tid >> 6, lane = tid & 63;
  const int wm = wid >> 2, wn = wid & 3;
  const int lr = lane & 15, hi = lane >> 4;
  const int srow = lane >> 2;
  const int scol = ((lane & 3) ^ ((lane >> 3) & 3)) * 8;   // pre-swizzled source col
  const int sx   = (hi ^ ((lr >> 1) & 3)) * 8;             // swizzled read slot
  f16* As = (f16*)(smem);            // [4][8192] halves = 65536 B
  f16* Bs = (f16*)(smem + 65536);    // [4][8192]
  const int cb0 = wid * 2, cb1 = wid * 2 + 1;
  const int n0 = ng * 256;

  for (int mg = 0; mg < 16; ++mg) {
    // readiness: all lstm blocks completed step 8*mg+7 (gready >= 8mg+8)
    if (wid == 0) {
      const unsigned tgt = (unsigned)(8 * mg + 8);
      for (;;) {
        unsigned g = __hip_atomic_load(gready, __ATOMIC_RELAXED, __HIP_MEMORY_SCOPE_AGENT);
        if (g >= tgt) break;
        __builtin_amdgcn_s_sleep(64);
      }
    }
    __syncthreads();

    const int m0 = mg * 256;
    f32x4 acc[8][4] = {};

    auto STAGE = [&](int kt) {
      const int k0 = kt << 5, buf = kt & 3;
      gld_lds16(HS     + (size_t)(m0 + cb0 * 16 + srow) * HID + k0 + scol, As + buf * 8192 + cb0 * 512);
      gld_lds16(Wout16 + (size_t)(n0 + cb0 * 16 + srow) * HID + k0 + scol, Bs + buf * 8192 + cb0 * 512);
      gld_lds16(HS     + (size_t)(m0 + cb1 * 16 + srow) * HID + k0 + scol, As + buf * 8192 + cb1 * 512);
      gld_lds16(Wout16 + (size_t)(n0 + cb1 * 16 + srow) * HID + k0 + scol, Bs + buf * 8192 + cb1 * 512);
    };

    STAGE(0); STAGE(1); STAGE(2);
    for (int kt = 0; kt < 32; ++kt) {
      if (kt < 30)       asm volatile("s_waitcnt vmcnt(8)" ::: "memory");
      else if (kt == 30) asm volatile("s_waitcnt vmcnt(4)" ::: "memory");
      else               asm volatile("s_waitcnt vmcnt(0)" ::: "memory");
      __builtin_amdgcn_s_barrier();
      if (kt + 3 < 32) STAGE(kt + 3);
      const f16* as = As + (kt & 3) * 8192;
      const f16* bs = Bs + (kt & 3) * 8192;
      f16x8 af[8], bf[4];
      #pragma unroll
      for (int mt = 0; mt < 8; ++mt)
        af[mt] = *(const f16x8*)&as[(wm * 128 + mt * 16 + lr) * 32 + sx];
      #pragma unroll
      for (int nt = 0; nt < 4; ++nt)
        bf[nt] = *(const f16x8*)&bs[(wn * 64 + nt * 16 + lr) * 32 + sx];
      __builtin_amdgcn_s_setprio(1);
      #pragma unroll
      for (int mt = 0; mt < 8; ++mt)
        #pragma unroll
        for (int nt = 0; nt < 4; ++nt)
          acc[mt][nt] = __builtin_amdgcn_mfma_f32_16x16x32_f16(af[mt], bf[nt], acc[mt][nt], 0, 0, 0);
      __builtin_amdgcn_s_setprio(0);
    }

    // epilogue: un-permute rows (m' = t*32+b -> out row b*128+t), add bias,
    // NON-TEMPORAL stores (out is write-once; keep it out of the caches)
    #pragma unroll
    for (int nt = 0; nt < 4; ++nt) {
      int col = n0 + wn * 64 + nt * 16 + lr;
      float bv = b_out[col];
      #pragma unroll
      for (int mt = 0; mt < 8; ++mt) {
        int mbase = m0 + wm * 128 + mt * 16 + hi * 4;
        #pragma unroll
        for (int p = 0; p < 4; ++p) {
          int mp = mbase + p;
          int orow = (mp & 31) * 128 + (mp >> 5);
          __builtin_nontemporal_store(acc[mt][nt][p] + bv,
                                      &out[(size_t)orow * VOC + col]);
        }
      }
    }
    __syncthreads();   // all frag reads done before next tile's STAGE overwrites LDS
  }
}

__global__ __launch_bounds__(512, 1) void fused_kernel(
    const f16* __restrict__ Whh16, const float* __restrict__ XG2,
    const f16* __restrict__ h0f, f16* __restrict__ HS,
    const f16* __restrict__ Wout16, const float* __restrict__ b_out,
    float* __restrict__ out, unsigned* __restrict__ bar,
    unsigned* __restrict__ gready) {
  __shared__ __align__(16) char smem[SM_SIZE];
  if (blockIdx.x < NLSTM) {
    lstm_role(Whh16, XG2, h0f, HS, bar, gready, smem);
  } else if (blockIdx.x < NLSTM + NCOL) {
    worker_role(HS, Wout16, b_out, out, gready, smem);
  }
}

extern "C" void kernel_launch(void* const* d_in, const int* in_sizes, int n_in,
                              void* d_out, int out_size, void* d_ws, size_t ws_size,
                              hipStream_t stream) {
  const float* z     = (const float*)d_in[0];
  const int*   x     = (const int*)d_in[1];
  const float* W_h   = (const float*)d_in[2];
  const float* b_h   = (const float*)d_in[3];
  const float* emb   = (const float*)d_in[4];
  const float* W_ih  = (const float*)d_in[5];
  const float* W_hh  = (const float*)d_in[6];
  const float* b_ih  = (const float*)d_in[7];
  const float* b_hh  = (const float*)d_in[8];
  const float* W_out = (const float*)d_in[9];
  const float* b_out = (const float*)d_in[10];
  float* out = (float*)d_out;

  char* ws = (char*)d_ws;
  size_t off = 0;
  auto carve = [&](size_t n) { char* p = ws + off; off += (n + 255) & ~(size_t)255; return p; };
  f16*   E16    = (f16*)carve((size_t)BT * DE * 2);     // 4 MB
  f16*   Wih16  = (f16*)carve((size_t)G4 * DE * 2);     // 4 MB
  f16*   Whh16  = (f16*)carve((size_t)G4 * HID * 2);    // 8 MB
  f16*   Wout16 = (f16*)carve((size_t)VOC * HID * 2);   // 64 MB
  float* XG2    = (float*)carve((size_t)BT * G4 * 4);   // 64 MB, [g][b][t]
  f16*   HS     = (f16*)carve((size_t)BT * HID * 2);    // 8 MB, t-major rows
  f16*   h0f    = (f16*)carve((size_t)Bb * HID * 2);
  float* bs     = (float*)carve((size_t)G4 * 4);
  unsigned* bar    = (unsigned*)carve(256);
  unsigned* gready = (unsigned*)carve(256);

  (void)hipMemsetAsync(bar, 0, 512, stream);   // bar + gready (contiguous)

  cvt3_kernel<<<2048, 256, 0, stream>>>(W_ih,  Wih16,  G4 * DE / 4,
                                        W_hh,  Whh16,  G4 * HID / 4,
                                        W_out, Wout16, VOC * HID / 4);
  gather_kernel<<<BT * DE / 8 / 256, 256, 0, stream>>>(emb, x, E16);
  bsum_kernel<<<16, 256, 0, stream>>>(b_ih, b_hh, bs, G4);
  h0_kernel<<<128, 256, 0, stream>>>(z, W_h, b_h, h0f);

  dim3 g1(G4 / 128, BT / 128);     // 32 x 32
  gemmxg_kernel<<<g1, 256, 0, stream>>>(E16, Wih16, bs, XG2, BT, G4, DE);

  fused_kernel<<<256, 512, 0, stream>>>(Whh16, XG2, h0f, HS, Wout16, b_out, out,
                                        bar, gready);
}